// Round 2
// baseline (218.661 us; speedup 1.0000x reference)
//
#include <hip/hip_runtime.h>

// Problem constants
#define BSEQ 64
#define LSEQ 512
#define CCH  1024
#define NT   7            // NUM_TAGS
#define NC   5            // real classes (labels are always 0..4)
#define NTOK (BSEQ*LSEQ)  // 32768
#define START_TAG 5
#define STOP_TAG  6
#define NEGV (-10000.0f)
#define GRID_LOGITS 1024  // k_logits assumes exactly this grid (8 iters/wave, 1 row/iter)

typedef float vfloat4 __attribute__((ext_vector_type(4)));

// ---------------- DPP wave64 sum (result lands in lane 63) ----------------
template<int CTRL, int RMASK, int BMASK>
__device__ __forceinline__ float dpp_add(float x) {
    int y = __builtin_amdgcn_update_dpp(0, __float_as_int(x), CTRL, RMASK, BMASK, true);
    return x + __int_as_float(y);
}
__device__ __forceinline__ float wave_sum(float x) {
    x = dpp_add<0x111, 0xF, 0xF>(x);  // row_shr:1
    x = dpp_add<0x112, 0xF, 0xF>(x);  // row_shr:2
    x = dpp_add<0x114, 0xF, 0xF>(x);  // row_shr:4
    x = dpp_add<0x118, 0xF, 0xF>(x);  // row_shr:8  -> lane15 of each row16 has row sum
    x = dpp_add<0x142, 0xA, 0xF>(x);  // row_bcast:15 into rows 1,3
    x = dpp_add<0x143, 0xC, 0xF>(x);  // row_bcast:31 into rows 2,3 -> lane63 = total
    return x;
}

// 5-way log-sum-exp helper
__device__ __forceinline__ float lse5(const float v0, const float v1, const float v2,
                                      const float v3, const float v4) {
    float m = fmaxf(fmaxf(fmaxf(v0, v1), fmaxf(v2, v3)), v4);
    float s = __expf(v0 - m) + __expf(v1 - m) + __expf(v2 - m)
            + __expf(v3 - m) + __expf(v4 - m);
    return m + __logf(s);
}

// ---------------- Kernel 1: logits (X @ W^T + b), labels copy, score zero ----------------
// R5 theory: inferred k_logits ~45us (~2.9 TB/s) from dur decomposition
// (211 = 2x79 harness fill + k_logits + ~8 k_crf). Stream BW scales with
// per-wave bytes in flight (R4 fix doubled it, 1.9->2.9 TB/s). This version:
// 1 row/iter x 8 iters, 5-deep rolling register pipeline -> 4 rows (16 KB)
// per wave in flight steady-state (2x the old ping-pong), 256 KB/CU.
// Plain loads (nt dropped: no L2 competition during this kernel; the 6.29 TB/s
// copy ubench uses plain float4). X prologue issued BEFORE W staging so the
// first 4 rows ride under the staging loads + barrier drain.
// VGPR budget: 5 bufs x 4 float4 = 80 + acc 7 + misc ~ 110 -> stays under the
// 128-VGPR occupancy cliff (m69: waves/SIMD halve at 64/128/256) = 16 waves/CU.
__global__ __launch_bounds__(256)
void k_logits(const float* __restrict__ X, const float* __restrict__ W,
              const float* __restrict__ bvec, const int* __restrict__ lab,
              float* __restrict__ out)
{
    __shared__ float Wl[NT][CCH];   // 28 KB
    __shared__ float bl[NT];

    const int lane = threadIdx.x & 63;
    const int wid  = (blockIdx.x * 256 + threadIdx.x) >> 6;   // 0..4095
    const int nw   = (GRID_LOGITS * 256) >> 6;                // 4096 waves

    vfloat4 xv[5][4];   // [buf][k-chunk] -- static indices after full unroll

    // prologue: issue rows 0..3 of this wave's stream (16 KB in flight)
    #pragma unroll
    for (int p = 0; p < 4; p++) {
        const vfloat4* xr = (const vfloat4*)(X + (size_t)(wid + p * nw) * CCH);
        #pragma unroll
        for (int k = 0; k < 4; k++) xv[p][k] = xr[k*64 + lane];
    }

    // stage W (rides behind the X prologue; barrier drain covers both)
    {
        const vfloat4* W4  = (const vfloat4*)W;
        vfloat4*       Wl4 = (vfloat4*)(&Wl[0][0]);
        for (int i = threadIdx.x; i < NT*CCH/4; i += 256) Wl4[i] = W4[i];
        if (threadIdx.x < NT) bl[threadIdx.x] = bvec[threadIdx.x];
    }
    __syncthreads();

    float* outP = out + 1 + NTOK;

    #pragma unroll
    for (int it = 0; it < 8; ++it) {
        const int buf = it % 5;
        // prefetch row it+4 into buf (it+4)%5 == (it-1)%5 (freed last iter)
        if (it < 4) {
            const vfloat4* xr = (const vfloat4*)(X + (size_t)(wid + (it + 4) * nw) * CCH);
            const int nb = (it + 4) % 5;
            #pragma unroll
            for (int k = 0; k < 4; k++) xv[nb][k] = xr[k*64 + lane];
        }

        float acc[NT];
        #pragma unroll
        for (int t = 0; t < NT; t++) acc[t] = 0.0f;

        #pragma unroll
        for (int k = 0; k < 4; k++) {
            const int cb = (k*64 + lane) * 4;
            #pragma unroll
            for (int t = 0; t < NT; t++) {
                const vfloat4 wv = *(const vfloat4*)(&Wl[t][cb]);   // unit-stride b128, conflict-free
                acc[t] = fmaf(xv[buf][k].x, wv.x,
                         fmaf(xv[buf][k].y, wv.y,
                         fmaf(xv[buf][k].z, wv.z,
                         fmaf(xv[buf][k].w, wv.w, acc[t]))));
            }
        }

        const size_t row = (size_t)(wid + it * nw);
        #pragma unroll
        for (int t = 0; t < NT; t++) {
            float s = wave_sum(acc[t]);
            if (lane == 63) outP[row * NT + t] = s + bl[t];
        }
    }

    // labels as float + zero the score slot
    for (int i = blockIdx.x * 256 + threadIdx.x; i < NTOK; i += GRID_LOGITS * 256)
        out[1 + i] = (float)lab[i];
    if (blockIdx.x == 0 && threadIdx.x == 0) out[0] = 0.0f;
}

// ---------------- Kernel 2: CRF NLL, 5-class log-semiring chunked scan ----------------
// (unchanged from the 209.7us version -- structurally ~5-8us; left identical
// for clean attribution of this round's delta to k_logits.)
// transitions[START,:]=NEG and [:,STOP]=NEG make the recurrence exactly 5x5 in
// fp32 (START enters only via step-0 injection u[k]=T[k,START]+e0[k]; STOP only
// at the final fold; all other START/STOP terms are exp(-10000-m) == 0.0f).
// Chunk 0 covers steps 1..7, chunks 1..63 cover 8 steps. 64 blocks x 320 thr
// (= 64 chunks x 5 basis). Tree-combine 64 5x5 matrices, fold u and T[STOP,:].
__global__ __launch_bounds__(320)
void k_crf(const float* __restrict__ dout_ro, const int* __restrict__ lab,
           const float* __restrict__ trans, float* __restrict__ score)
{
    __shared__ float E[LSEQ*NT];   // 3584 floats; reused as matrix buffer A after recurrence
    __shared__ float M2[32*25];    // ping-pong buffer B
    __shared__ float T[49];
    __shared__ float u_sh[NC];     // fv after step 0 (START injection)
    __shared__ float gred[5];

    const int b   = blockIdx.x;
    const int tid = threadIdx.x;
    const float* feats = dout_ro + 1 + NTOK + (size_t)b * (LSEQ*NT);

    for (int i = tid; i < LSEQ*NT; i += 320) E[i] = feats[i];
    if (tid < 49) T[tid] = trans[tid];
    __syncthreads();

    if (tid < NC) u_sh[tid] = T[tid*NT + START_TAG] + E[tid];   // e0[k] before E is overwritten

    // ---- gold score (parallel over tokens) ----
    float g = 0.0f;
    for (int l = tid; l < LSEQ; l += 320) {
        const int t  = lab[b*LSEQ + l];
        const int tp = (l == 0) ? START_TAG : lab[b*LSEQ + l - 1];
        g += E[l*NT + t] + T[t*NT + tp];
    }
    if (tid == 0) g += T[STOP_TAG*NT + lab[b*LSEQ + LSEQ - 1]];
    {
        float gs = wave_sum(g);
        if ((tid & 63) == 63) gred[tid >> 6] = gs;
    }

    // ---- chunk basis recurrences (5x5, all in registers) ----
    float TR[NC*NC];
    #pragma unroll
    for (int j = 0; j < NC; j++)
        #pragma unroll
        for (int k = 0; k < NC; k++) TR[j*NC + k] = T[j*NT + k];

    const int chunk = tid / NC;
    const int basis = tid - chunk * NC;
    float fv[NC];
    #pragma unroll
    for (int j = 0; j < NC; j++) fv[j] = (j == basis) ? 0.0f : NEGV;

    const int l0    = (chunk == 0) ? 1 : chunk * 8;
    const int steps = (chunk == 0) ? 7 : 8;
    for (int s = 0; s < steps; s++) {
        const int l = l0 + s;
        float fn[NC];
        #pragma unroll
        for (int j = 0; j < NC; j++) {
            fn[j] = lse5(fv[0] + TR[j*NC+0], fv[1] + TR[j*NC+1], fv[2] + TR[j*NC+2],
                         fv[3] + TR[j*NC+3], fv[4] + TR[j*NC+4]) + E[l*NT + j];
        }
        #pragma unroll
        for (int j = 0; j < NC; j++) fv[j] = fn[j];
    }
    __syncthreads();   // all E reads done; safe to overwrite with matrices
    #pragma unroll
    for (int j = 0; j < NC; j++) E[chunk*25 + basis*NC + j] = fv[j];

    // ---- tree combine: C[i][j] = lse_k(A[i][k] + B[k][j]), chronological L->R ----
    int n = 64, cur = 0;
    while (n > 1) {
        __syncthreads();
        const float* in = (cur == 0) ? (const float*)E : (const float*)M2;
        float*       ob = (cur == 0) ? M2 : E;
        const int half = n >> 1;
        for (int e2 = tid; e2 < half*25; e2 += 320) {
            const int p = e2 / 25, r = e2 - p*25;
            const int i = r / NC, j = r - (r/NC)*NC;
            const float* A  = in + (2*p)*25 + i*NC;
            const float* Bm = in + (2*p + 1)*25 + j;
            ob[p*25 + r] = lse5(A[0] + Bm[0], A[1] + Bm[NC], A[2] + Bm[2*NC],
                                A[3] + Bm[3*NC], A[4] + Bm[4*NC]);
        }
        cur ^= 1; n = half;
    }
    __syncthreads();

    if (tid == 0) {
        float gg = gred[0] + gred[1] + gred[2] + gred[3] + gred[4];
        const float* M = (cur == 0) ? (const float*)E : (const float*)M2;  // final 5x5
        float v[NC];
        #pragma unroll
        for (int j = 0; j < NC; j++)
            v[j] = lse5(u_sh[0] + M[0*NC+j], u_sh[1] + M[1*NC+j], u_sh[2] + M[2*NC+j],
                        u_sh[3] + M[3*NC+j], u_sh[4] + M[4*NC+j]);
        float fwd = lse5(v[0] + T[STOP_TAG*NT+0], v[1] + T[STOP_TAG*NT+1],
                         v[2] + T[STOP_TAG*NT+2], v[3] + T[STOP_TAG*NT+3],
                         v[4] + T[STOP_TAG*NT+4]);
        atomicAdd(score, fwd - gg);
    }
}

extern "C" void kernel_launch(void* const* d_in, const int* in_sizes, int n_in,
                              void* d_out, int out_size, void* d_ws, size_t ws_size,
                              hipStream_t stream) {
    const float* X     = (const float*)d_in[0];   // fuse_embeddings [32768,1024]
    const int*   lab   = (const int*)  d_in[1];   // label_class [32768]
    const float* W     = (const float*)d_in[2];   // [7,1024]
    const float* bvec  = (const float*)d_in[3];   // [7]
    const float* trans = (const float*)d_in[4];   // [7,7]
    float* out = (float*)d_out;

    k_logits<<<GRID_LOGITS, 256, 0, stream>>>(X, W, bvec, lab, out);
    k_crf<<<BSEQ, 320, 0, stream>>>(out, lab, trans, out);
}

// Round 3
// 214.044 us; speedup vs baseline: 1.0216x; 1.0216x over previous
//
#include <hip/hip_runtime.h>

// Problem constants
#define BSEQ 64
#define LSEQ 512
#define CCH  1024
#define NT   7            // NUM_TAGS
#define NC   5            // real classes (labels are always 0..4)
#define NTOK (BSEQ*LSEQ)  // 32768
#define START_TAG 5
#define STOP_TAG  6
#define NEGV (-10000.0f)
#define GRID_LOGITS 1024  // k_logits assumes exactly this grid (8 rows/wave)

typedef float vfloat4 __attribute__((ext_vector_type(4)));

// ---------------- DPP wave64 sum (result lands in lane 63) ----------------
template<int CTRL, int RMASK, int BMASK>
__device__ __forceinline__ float dpp_add(float x) {
    int y = __builtin_amdgcn_update_dpp(0, __float_as_int(x), CTRL, RMASK, BMASK, true);
    return x + __int_as_float(y);
}
__device__ __forceinline__ float wave_sum(float x) {
    x = dpp_add<0x111, 0xF, 0xF>(x);  // row_shr:1
    x = dpp_add<0x112, 0xF, 0xF>(x);  // row_shr:2
    x = dpp_add<0x114, 0xF, 0xF>(x);  // row_shr:4
    x = dpp_add<0x118, 0xF, 0xF>(x);  // row_shr:8  -> lane15 of each row16 has row sum
    x = dpp_add<0x142, 0xA, 0xF>(x);  // row_bcast:15 into rows 1,3
    x = dpp_add<0x143, 0xC, 0xF>(x);  // row_bcast:31 into rows 2,3 -> lane63 = total
    return x;
}

// 5-way log-sum-exp helper
__device__ __forceinline__ float lse5(const float v0, const float v1, const float v2,
                                      const float v3, const float v4) {
    float m = fmaxf(fmaxf(fmaxf(v0, v1), fmaxf(v2, v3)), v4);
    float s = __expf(v0 - m) + __expf(v1 - m) + __expf(v2 - m)
            + __expf(v3 - m) + __expf(v4 - m);
    return m + __logf(s);
}

// ---------------- Kernel 1: logits (X @ W^T + b), labels copy, score zero ----------------
// R6: post-mortem of R5 (218.7 vs 211.4): deeper in-flight alone didn't help;
// dropping nontemporal regressed -> NT restored (R4's proven element: NT loads
// bypass L1 allocation, carrying more misses in flight per CU).
// New structure: k-phase OUTER, rows inner. Per 256-channel phase the 7 W
// fragments are hoisted from LDS into VGPRs once (7 ds_read_b128/phase), so
// the inner row loop is pure FMA on registers. LDS reads/wave: 56 vs 224 in
// the row-outer version; per-row compute ~600 -> ~400 cyc, thinning the
// post-arrival convoy that throttled load issue (VALUBusy ~9% signature).
// 8 global phases (2 row-groups x 4 chans-phases); 3-slot rolling X prefetch
// keeps ~8 KB/wave in flight (R4's proven depth).
// VGPR: acc 28 + wreg 28 + xb 48 + misc ~ 120 -> under the 128 cliff, 16 waves/CU.
__global__ __launch_bounds__(256)
void k_logits(const float* __restrict__ X, const float* __restrict__ W,
              const float* __restrict__ bvec, const int* __restrict__ lab,
              float* __restrict__ out)
{
    __shared__ float Wl[NT][CCH];   // 28 KB
    __shared__ float bl[NT];

    const int lane = threadIdx.x & 63;
    const int wid  = (blockIdx.x * 256 + threadIdx.x) >> 6;   // 0..4095
    const int nw   = (GRID_LOGITS * 256) >> 6;                // 4096 waves

    vfloat4 xb[3][4];   // [phase-slot][row j] -- all indices static after unroll

    // phase p (0..7): group G=p>>2 (rows wid+(G*4+j)*nw), channel chunk k=p&3.
    // issue loads for phase p into slot p%3.
    #define ISSUE_PHASE(p, slot)                                                   \
        if ((p) < 8) {                                                             \
            const int G_ = (p) >> 2, k_ = (p) & 3;                                 \
            _Pragma("unroll")                                                      \
            for (int j = 0; j < 4; j++) {                                          \
                const size_t row_ = (size_t)(wid + (G_*4 + j) * nw);               \
                const vfloat4* xp_ = (const vfloat4*)(X + row_ * CCH) + (k_*64 + lane); \
                xb[slot][j] = __builtin_nontemporal_load(xp_);                     \
            }                                                                      \
        }

    // prologue: phases 0,1 in flight before W staging; barrier drain covers both
    ISSUE_PHASE(0, 0)
    ISSUE_PHASE(1, 1)

    {
        const vfloat4* W4  = (const vfloat4*)W;
        vfloat4*       Wl4 = (vfloat4*)(&Wl[0][0]);
        for (int i = threadIdx.x; i < NT*CCH/4; i += 256) Wl4[i] = W4[i];
        if (threadIdx.x < NT) bl[threadIdx.x] = bvec[threadIdx.x];
    }
    __syncthreads();

    float* outP = out + 1 + NTOK;

    float acc[4][NT];
    #pragma unroll
    for (int j = 0; j < 4; j++)
        #pragma unroll
        for (int t = 0; t < NT; t++) acc[j][t] = 0.0f;

    #pragma unroll
    for (int p = 0; p < 8; ++p) {
        const int slot = p % 3;
        const int k    = p & 3;

        // prefetch phase p+2 into slot (p+2)%3 (holds phase p-1, consumed)
        ISSUE_PHASE(p + 2, (p + 2) % 3)

        // hoist this phase's W fragments into registers (7 ds_read_b128)
        vfloat4 wreg[NT];
        {
            const int cb = (k*64 + lane) * 4;
            #pragma unroll
            for (int t = 0; t < NT; t++)
                wreg[t] = *(const vfloat4*)(&Wl[t][cb]);   // unit-stride, conflict-free
        }

        // pure-register inner loop: 4 rows x 7 tags x 4 FMA
        #pragma unroll
        for (int j = 0; j < 4; j++) {
            #pragma unroll
            for (int t = 0; t < NT; t++) {
                acc[j][t] = fmaf(xb[slot][j].x, wreg[t].x,
                            fmaf(xb[slot][j].y, wreg[t].y,
                            fmaf(xb[slot][j].z, wreg[t].z,
                            fmaf(xb[slot][j].w, wreg[t].w, acc[j][t]))));
            }
        }

        // end of a row-group (k==3): reduce + store + reset acc
        if (k == 3) {
            const int G = p >> 2;
            #pragma unroll
            for (int j = 0; j < 4; j++) {
                const size_t row = (size_t)(wid + (G*4 + j) * nw);
                #pragma unroll
                for (int t = 0; t < NT; t++) {
                    float s = wave_sum(acc[j][t]);
                    if (lane == 63) outP[row * NT + t] = s + bl[t];
                    acc[j][t] = 0.0f;
                }
            }
        }
    }
    #undef ISSUE_PHASE

    // labels as float + zero the score slot
    for (int i = blockIdx.x * 256 + threadIdx.x; i < NTOK; i += GRID_LOGITS * 256)
        out[1 + i] = (float)lab[i];
    if (blockIdx.x == 0 && threadIdx.x == 0) out[0] = 0.0f;
}

// ---------------- Kernel 2: CRF NLL, 5-class log-semiring chunked scan ----------------
// (unchanged -- left identical for clean attribution of this round's delta.)
__global__ __launch_bounds__(320)
void k_crf(const float* __restrict__ dout_ro, const int* __restrict__ lab,
           const float* __restrict__ trans, float* __restrict__ score)
{
    __shared__ float E[LSEQ*NT];   // 3584 floats; reused as matrix buffer A after recurrence
    __shared__ float M2[32*25];    // ping-pong buffer B
    __shared__ float T[49];
    __shared__ float u_sh[NC];     // fv after step 0 (START injection)
    __shared__ float gred[5];

    const int b   = blockIdx.x;
    const int tid = threadIdx.x;
    const float* feats = dout_ro + 1 + NTOK + (size_t)b * (LSEQ*NT);

    for (int i = tid; i < LSEQ*NT; i += 320) E[i] = feats[i];
    if (tid < 49) T[tid] = trans[tid];
    __syncthreads();

    if (tid < NC) u_sh[tid] = T[tid*NT + START_TAG] + E[tid];   // e0[k] before E is overwritten

    // ---- gold score (parallel over tokens) ----
    float g = 0.0f;
    for (int l = tid; l < LSEQ; l += 320) {
        const int t  = lab[b*LSEQ + l];
        const int tp = (l == 0) ? START_TAG : lab[b*LSEQ + l - 1];
        g += E[l*NT + t] + T[t*NT + tp];
    }
    if (tid == 0) g += T[STOP_TAG*NT + lab[b*LSEQ + LSEQ - 1]];
    {
        float gs = wave_sum(g);
        if ((tid & 63) == 63) gred[tid >> 6] = gs;
    }

    // ---- chunk basis recurrences (5x5, all in registers) ----
    float TR[NC*NC];
    #pragma unroll
    for (int j = 0; j < NC; j++)
        #pragma unroll
        for (int k = 0; k < NC; k++) TR[j*NC + k] = T[j*NT + k];

    const int chunk = tid / NC;
    const int basis = tid - chunk * NC;
    float fv[NC];
    #pragma unroll
    for (int j = 0; j < NC; j++) fv[j] = (j == basis) ? 0.0f : NEGV;

    const int l0    = (chunk == 0) ? 1 : chunk * 8;
    const int steps = (chunk == 0) ? 7 : 8;
    for (int s = 0; s < steps; s++) {
        const int l = l0 + s;
        float fn[NC];
        #pragma unroll
        for (int j = 0; j < NC; j++) {
            fn[j] = lse5(fv[0] + TR[j*NC+0], fv[1] + TR[j*NC+1], fv[2] + TR[j*NC+2],
                         fv[3] + TR[j*NC+3], fv[4] + TR[j*NC+4]) + E[l*NT + j];
        }
        #pragma unroll
        for (int j = 0; j < NC; j++) fv[j] = fn[j];
    }
    __syncthreads();   // all E reads done; safe to overwrite with matrices
    #pragma unroll
    for (int j = 0; j < NC; j++) E[chunk*25 + basis*NC + j] = fv[j];

    // ---- tree combine: C[i][j] = lse_k(A[i][k] + B[k][j]), chronological L->R ----
    int n = 64, cur = 0;
    while (n > 1) {
        __syncthreads();
        const float* in = (cur == 0) ? (const float*)E : (const float*)M2;
        float*       ob = (cur == 0) ? M2 : E;
        const int half = n >> 1;
        for (int e2 = tid; e2 < half*25; e2 += 320) {
            const int p = e2 / 25, r = e2 - p*25;
            const int i = r / NC, j = r - (r/NC)*NC;
            const float* A  = in + (2*p)*25 + i*NC;
            const float* Bm = in + (2*p + 1)*25 + j;
            ob[p*25 + r] = lse5(A[0] + Bm[0], A[1] + Bm[NC], A[2] + Bm[2*NC],
                                A[3] + Bm[3*NC], A[4] + Bm[4*NC]);
        }
        cur ^= 1; n = half;
    }
    __syncthreads();

    if (tid == 0) {
        float gg = gred[0] + gred[1] + gred[2] + gred[3] + gred[4];
        const float* M = (cur == 0) ? (const float*)E : (const float*)M2;  // final 5x5
        float v[NC];
        #pragma unroll
        for (int j = 0; j < NC; j++)
            v[j] = lse5(u_sh[0] + M[0*NC+j], u_sh[1] + M[1*NC+j], u_sh[2] + M[2*NC+j],
                        u_sh[3] + M[3*NC+j], u_sh[4] + M[4*NC+j]);
        float fwd = lse5(v[0] + T[STOP_TAG*NT+0], v[1] + T[STOP_TAG*NT+1],
                         v[2] + T[STOP_TAG*NT+2], v[3] + T[STOP_TAG*NT+3],
                         v[4] + T[STOP_TAG*NT+4]);
        atomicAdd(score, fwd - gg);
    }
}

extern "C" void kernel_launch(void* const* d_in, const int* in_sizes, int n_in,
                              void* d_out, int out_size, void* d_ws, size_t ws_size,
                              hipStream_t stream) {
    const float* X     = (const float*)d_in[0];   // fuse_embeddings [32768,1024]
    const int*   lab   = (const int*)  d_in[1];   // label_class [32768]
    const float* W     = (const float*)d_in[2];   // [7,1024]
    const float* bvec  = (const float*)d_in[3];   // [7]
    const float* trans = (const float*)d_in[4];   // [7,7]
    float* out = (float*)d_out;

    k_logits<<<GRID_LOGITS, 256, 0, stream>>>(X, W, bvec, lab, out);
    k_crf<<<BSEQ, 320, 0, stream>>>(out, lab, trans, out);
}